// Round 2
// baseline (4880.914 us; speedup 1.0000x reference)
//
#include <hip/hip_runtime.h>

#define TPB 256
#define PSTR 36   // LDS pixel stride (floats): 32ch + 4 pad -> bank spread + 16B align

// ---------------- workspace layout (bytes) ----------------
// gp   u64 [128*900]          @ 0          921600
// widx u32 [128*900]          @ 921600     460800
// dgrid f32 [128*900]         @ 1382400    460800
// wT   f32 [16*25*8*32*4]     @ 1843200    1638400   fwd weights [j][t][g][ci][c]
// wTb  f32 [16*25*8*32*4]     @ 3481600    1638400   bwd weights (tap-flipped, ch-swapped)
// acts f32 [128*17*32*64]     @ 5120000    17825792  activations [b][l][ch][pix]
// total ~22.9 MB

static __device__ __forceinline__ unsigned long long dkey(double d) {
  unsigned long long b = (unsigned long long)__double_as_longlong(d);
  return (b & 0x8000000000000000ull) ? ~b : (b | 0x8000000000000000ull);
}

// Deterministic fp64 point-MLP forward (explicit fma -> bit-identical across kernels)
static __device__ __forceinline__ void mlp_forward(
    float px, float py, float at,
    const float* __restrict__ W1, const float* __restrict__ b1,
    const float* __restrict__ W2, const float* __restrict__ b2,
    const float* __restrict__ W3, const float* __restrict__ b3,
    int& c0, int& c1, double& dx, double& dy, double& dist,
    double a1[16], double a2[16], double f[4]) {
  c0 = (int)floorf(px); c0 = c0 < 0 ? 0 : (c0 > 14 ? 14 : c0);
  c1 = (int)floorf(py); c1 = c1 < 0 ? 0 : (c1 > 14 ? 14 : c1);
  dx = (double)px - ((double)c0 + 0.5);
  dy = (double)py - ((double)c1 + 0.5);
  dist = sqrt(fma(dx, dx, fma(dy, dy, 1e-12)));
  double datt = (double)at;
#pragma unroll
  for (int j = 0; j < 16; ++j) {
    double z = fma(dist, (double)W1[j], fma(datt, (double)W1[16 + j], (double)b1[j]));
    a1[j] = z > 0.0 ? z : expm1(z);
  }
#pragma unroll
  for (int j = 0; j < 16; ++j) {
    double z = (double)b2[j];
#pragma unroll
    for (int i = 0; i < 16; ++i) z = fma(a1[i], (double)W2[i * 16 + j], z);
    a2[j] = z > 0.0 ? z : expm1(z);
  }
#pragma unroll
  for (int k = 0; k < 4; ++k) {
    double ff = (double)b3[k];
#pragma unroll
    for (int i = 0; i < 16; ++i) ff = fma(a2[i], (double)W3[i * 4 + k], ff);
    f[k] = ff;
  }
}

__global__ __launch_bounds__(TPB)
void k_init(unsigned long long* __restrict__ gp, unsigned int* __restrict__ widx) {
  int e = blockIdx.x * TPB + threadIdx.x;
  if (e < 128 * 900) { gp[e] = 0x8000000000000000ull; widx[e] = 0xFFFFFFFFu; }
}

// Transpose conv weights: wT[j][t][g][m=ci][c] = cw[j][co=g*4+c][ci=m][t]
//                         wTb[j][t][g][m=co][c] = cw[j][co=m][ci=g*4+c][24-t]
__global__ __launch_bounds__(TPB)
void k_wtrans(const float* __restrict__ cw, float* __restrict__ wT, float* __restrict__ wTb) {
  int i = blockIdx.x * TPB + threadIdx.x;
  if (i >= 409600) return;
  int c = i & 3;
  int m = (i >> 2) & 31;
  int g = (i >> 7) & 7;
  int jt = i >> 10;
  int t = jt % 25;
  int j = jt / 25;
  wT[i]  = cw[((size_t)(j * 32 + (g * 4 + c)) * 32 + m) * 25 + t];
  wTb[i] = cw[((size_t)(j * 32 + m) * 32 + (g * 4 + c)) * 25 + (24 - t)];
}

__global__ __launch_bounds__(TPB)
void k_point_fwd(const float* __restrict__ points, const float* __restrict__ attrs,
                 const float* __restrict__ W1, const float* __restrict__ b1,
                 const float* __restrict__ W2, const float* __restrict__ b2,
                 const float* __restrict__ W3, const float* __restrict__ b3,
                 unsigned long long* __restrict__ gp) {
  int gid = blockIdx.x * TPB + threadIdx.x;  // exactly 2^21 threads
  float px = points[2 * gid], py = points[2 * gid + 1];
  float at = attrs[gid];
  int c0, c1; double dx, dy, dist, a1[16], a2[16], f[4];
  mlp_forward(px, py, at, W1, b1, W2, b2, W3, b3, c0, c1, dx, dy, dist, a1, a2, f);
  int b = gid >> 14;
  size_t base = (size_t)b * 900 + (size_t)(c0 * 15 + c1) * 4;
#pragma unroll
  for (int k = 0; k < 4; ++k) atomicMax(&gp[base + k], dkey(f[k]));
}

__global__ __launch_bounds__(TPB)
void k_claim(const float* __restrict__ points, const float* __restrict__ attrs,
             const float* __restrict__ W1, const float* __restrict__ b1,
             const float* __restrict__ W2, const float* __restrict__ b2,
             const float* __restrict__ W3, const float* __restrict__ b3,
             const unsigned long long* __restrict__ gp, unsigned int* __restrict__ widx) {
  int gid = blockIdx.x * TPB + threadIdx.x;
  float px = points[2 * gid], py = points[2 * gid + 1];
  float at = attrs[gid];
  int c0, c1; double dx, dy, dist, a1[16], a2[16], f[4];
  mlp_forward(px, py, at, W1, b1, W2, b2, W3, b3, c0, c1, dx, dy, dist, a1, a2, f);
  int b = gid >> 14;
  size_t base = (size_t)b * 900 + (size_t)(c0 * 15 + c1) * 4;
#pragma unroll
  for (int k = 0; k < 4; ++k)
    if (dkey(f[k]) == gp[base + k]) atomicMin(&widx[base + k], (unsigned)(gid & 16383));
}

// 25-tap MAC block: per tap, 8 ds_read_b128 of 4 in-ch + 16 fma into 4 out-ch accs.
// wb is wave-uniform (s_load path); Rd is LDS [pix][ch] stride PSTR.
static __device__ __forceinline__ void conv_mac(const float* __restrict__ Rd, int tap_base,
                                                const float* __restrict__ wb,
                                                float& acc0, float& acc1, float& acc2, float& acc3) {
#pragma unroll
  for (int t = 0; t < 25; ++t) {
    const int po = ((t / 5) * 12 + (t % 5)) * PSTR;
    const float* wp = wb + t * 1024;
#pragma unroll
    for (int cib = 0; cib < 8; ++cib) {
      const float4 a4 = *(const float4*)&Rd[tap_base + po + cib * 4];
      const float* w16 = wp + cib * 16;
      acc0 = fmaf(w16[0],  a4.x, acc0); acc1 = fmaf(w16[1],  a4.x, acc1);
      acc2 = fmaf(w16[2],  a4.x, acc2); acc3 = fmaf(w16[3],  a4.x, acc3);
      acc0 = fmaf(w16[4],  a4.y, acc0); acc1 = fmaf(w16[5],  a4.y, acc1);
      acc2 = fmaf(w16[6],  a4.y, acc2); acc3 = fmaf(w16[7],  a4.y, acc3);
      acc0 = fmaf(w16[8],  a4.z, acc0); acc1 = fmaf(w16[9],  a4.z, acc1);
      acc2 = fmaf(w16[10], a4.z, acc2); acc3 = fmaf(w16[11], a4.z, acc3);
      acc0 = fmaf(w16[12], a4.w, acc0); acc1 = fmaf(w16[13], a4.w, acc1);
      acc2 = fmaf(w16[14], a4.w, acc2); acc3 = fmaf(w16[15], a4.w, acc3);
    }
  }
}

__global__ __launch_bounds__(512)
void k_cnn_fwd(const unsigned long long* __restrict__ gp,
               const float* __restrict__ c1w, const float* __restrict__ c1b,
               const float* __restrict__ bn1g, const float* __restrict__ bn1b,
               const float* __restrict__ wT, const float* __restrict__ cb,
               const float* __restrict__ bg, const float* __restrict__ bb,
               float* __restrict__ acts) {
  __shared__ float xin[900];
  __shared__ __align__(16) float buf[2][5184];  // [12x12 pix][36] x2 ping-pong
  const int tid = threadIdx.x;
  const int b = blockIdx.x;
  for (int t = tid; t < 10368; t += 512) ((float*)buf)[t] = 0.0f;
  for (int t = tid; t < 900; t += 512) {
    int c = t / 225, rem = t - c * 225;
    unsigned long long k = gp[(size_t)b * 900 + rem * 4 + c];
    long long bits = (k & 0x8000000000000000ull) ? (long long)(k & 0x7FFFFFFFFFFFFFFFull)
                                                 : ~(long long)k;
    xin[c * 225 + rem] = (float)__longlong_as_double(bits);
  }
  __syncthreads();
  const float rs = sqrtf(1.0f + 1e-5f);
  // conv1: 4x15x15 -> 32x8x8, stride 2, pad 2
  for (int k = tid; k < 2048; k += 512) {
    int co = k >> 6, pix = k & 63, y = pix >> 3, x = pix & 7;
    float acc = c1b[co];
    for (int ci = 0; ci < 4; ++ci)
#pragma unroll
      for (int ky = 0; ky < 5; ++ky) {
        int iy = 2 * y + ky - 2;
        if (iy < 0 || iy > 14) continue;
#pragma unroll
        for (int kx = 0; kx < 5; ++kx) {
          int ix = 2 * x + kx - 2;
          if (ix < 0 || ix > 14) continue;
          acc = fmaf(c1w[((co * 4 + ci) * 5 + ky) * 5 + kx], xin[ci * 225 + iy * 15 + ix], acc);
        }
      }
    float z = fmaf(acc, bn1g[co] / rs, bn1b[co]);
    float a = z > 0.f ? z : expm1f(z);
    buf[0][((y + 2) * 12 + (x + 2)) * PSTR + co] = a;
    acts[((size_t)(b * 17) * 32 + co) * 64 + pix] = a;
  }
  __syncthreads();
  const int wave = __builtin_amdgcn_readfirstlane(tid >> 6);  // 0..7, 4 out-ch each
  const int lane = tid & 63;
  const int y = lane >> 3, x = lane & 7;
  const int tap_base = (y * 12 + x) * PSTR;
  const int st_off = ((y + 2) * 12 + (x + 2)) * PSTR + wave * 4;
  float* B0 = buf[0];
  float* B1 = buf[1];
#pragma unroll 1
  for (int j = 0; j < 16; ++j) {
    const float* Rd = (j & 1) ? B1 : B0;
    float* Wr = (j & 1) ? B0 : B1;
    const float* wb = wT + ((size_t)(j * 25) * 8 + wave) * 128;
    const int cbase = j * 32 + wave * 4;
    float acc0 = cb[cbase], acc1 = cb[cbase + 1], acc2 = cb[cbase + 2], acc3 = cb[cbase + 3];
    conv_mac(Rd, tap_base, wb, acc0, acc1, acc2, acc3);
    float z0 = fmaf(acc0, bg[cbase] / rs, bb[cbase]);
    float z1 = fmaf(acc1, bg[cbase + 1] / rs, bb[cbase + 1]);
    float z2 = fmaf(acc2, bg[cbase + 2] / rs, bb[cbase + 2]);
    float z3 = fmaf(acc3, bg[cbase + 3] / rs, bb[cbase + 3]);
    float a0 = z0 > 0.f ? z0 : expm1f(z0);
    float a1 = z1 > 0.f ? z1 : expm1f(z1);
    float a2 = z2 > 0.f ? z2 : expm1f(z2);
    float a3 = z3 > 0.f ? z3 : expm1f(z3);
    *(float4*)&Wr[st_off] = make_float4(a0, a1, a2, a3);
    float* ap = acts + ((size_t)(b * 17 + j + 1) * 32 + wave * 4) * 64 + lane;
    ap[0] = a0; ap[64] = a1; ap[128] = a2; ap[192] = a3;
    __syncthreads();
  }
}

__global__ __launch_bounds__(512)
void k_cnn_bwd(const float* __restrict__ acts,
               const float* __restrict__ wTb, const float* __restrict__ bg,
               const float* __restrict__ c1w, const float* __restrict__ bn1g,
               float* __restrict__ dgrid) {
  __shared__ __align__(16) float buf[2][5184];
  const int tid = threadIdx.x;
  const int b = blockIdx.x;
  for (int t = tid; t < 10368; t += 512) ((float*)buf)[t] = 0.0f;
  __syncthreads();
  for (int k = tid; k < 2048; k += 512) {
    int pix = k >> 5, ch = k & 31;
    buf[0][((2 + (pix >> 3)) * 12 + 2 + (pix & 7)) * PSTR + ch] = 1.0f / 2048.0f;
  }
  __syncthreads();
  const float rs = sqrtf(1.0f + 1e-5f);
  const int wave = __builtin_amdgcn_readfirstlane(tid >> 6);
  const int lane = tid & 63;
  const int y = lane >> 3, x = lane & 7;
  const int tap_base = (y * 12 + x) * PSTR;
  const int st_off = ((y + 2) * 12 + (x + 2)) * PSTR + wave * 4;
  const int sch = tid >> 4;           // scale step: channel
  const int sp4 = (tid & 15) * 4;     // scale step: pixel quad
  float* B0 = buf[0];
  float* B1 = buf[1];
#pragma unroll 1
  for (int jj = 0; jj < 16; ++jj) {
    const int j = 15 - jj;
    float* G  = (jj & 1) ? B1 : B0;
    float* Wr = (jj & 1) ? B0 : B1;
    // scale: G *= elu'(act_{j+1}) * bg/rs
    {
      const float4 a = *(const float4*)&acts[((size_t)(b * 17 + j + 1) * 32 + sch) * 64 + sp4];
      const float sj = bg[j * 32 + sch] / rs;
#pragma unroll
      for (int q = 0; q < 4; ++q) {
        int pix = sp4 + q;
        int li = ((2 + (pix >> 3)) * 12 + 2 + (pix & 7)) * PSTR + sch;
        float av = q == 0 ? a.x : (q == 1 ? a.y : (q == 2 ? a.z : a.w));
        float d = (av > 0.f ? 1.f : av + 1.f) * sj;
        G[li] *= d;
      }
    }
    __syncthreads();
    // transposed conv (tap-flipped weights, channels swapped)
    const float* wb = wTb + ((size_t)(j * 25) * 8 + wave) * 128;
    float acc0 = 0.f, acc1 = 0.f, acc2 = 0.f, acc3 = 0.f;
    conv_mac(G, tap_base, wb, acc0, acc1, acc2, acc3);
    *(float4*)&Wr[st_off] = make_float4(acc0, acc1, acc2, acc3);
    __syncthreads();
  }
  // final grad lives in B0; scale by elu'(act_0) * bn1g/rs
  {
    const float4 a = *(const float4*)&acts[((size_t)(b * 17) * 32 + sch) * 64 + sp4];
    const float sj = bn1g[sch] / rs;
#pragma unroll
    for (int q = 0; q < 4; ++q) {
      int pix = sp4 + q;
      int li = ((2 + (pix >> 3)) * 12 + 2 + (pix & 7)) * PSTR + sch;
      float av = q == 0 ? a.x : (q == 1 ? a.y : (q == 2 ? a.z : a.w));
      float d = (av > 0.f ? 1.f : av + 1.f) * sj;
      B0[li] *= d;
    }
  }
  __syncthreads();
  // conv1 backward to the 4x15x15 grid input
  for (int e = tid; e < 900; e += 512) {
    int cid = e >> 2, ci = e & 3;
    int u = cid / 15, v = cid - u * 15;
    float acc = 0.f;
    for (int co = 0; co < 32; ++co) {
      const float* wp = c1w + (co * 4 + ci) * 25;
#pragma unroll
      for (int ky = 0; ky < 5; ++ky) {
        int t2 = u + 2 - ky;
        if (t2 < 0 || t2 > 14 || (t2 & 1)) continue;
        int yy = t2 >> 1;
#pragma unroll
        for (int kx = 0; kx < 5; ++kx) {
          int s2 = v + 2 - kx;
          if (s2 < 0 || s2 > 14 || (s2 & 1)) continue;
          int xq = s2 >> 1;
          acc = fmaf(wp[ky * 5 + kx], B0[((yy + 2) * 12 + (xq + 2)) * PSTR + co], acc);
        }
      }
    }
    dgrid[(size_t)b * 900 + e] = acc;
  }
}

__global__ __launch_bounds__(TPB)
void k_winner(const float* __restrict__ points, const float* __restrict__ attrs,
              const float* __restrict__ W1, const float* __restrict__ b1,
              const float* __restrict__ W2, const float* __restrict__ b2,
              const float* __restrict__ W3, const float* __restrict__ b3,
              const unsigned int* __restrict__ widx, const float* __restrict__ dgrid,
              float* __restrict__ dpoints, float* __restrict__ dattrs) {
  int e = blockIdx.x * TPB + threadIdx.x;  // exactly 115200
  unsigned pi = widx[e];
  if (pi == 0xFFFFFFFFu) return;
  float g = dgrid[e];
  if (g == 0.f) return;
  int b = e / 900;
  int r = e - b * 900;
  int ch = r & 3;
  size_t pidx = ((size_t)b << 14) + pi;
  float px = points[2 * pidx], py = points[2 * pidx + 1], at = attrs[pidx];
  int c0, c1; double dx, dy, dist, a1[16], a2[16], f[4];
  mlp_forward(px, py, at, W1, b1, W2, b2, W3, b3, c0, c1, dx, dy, dist, a1, a2, f);
  double gz2[16];
#pragma unroll
  for (int i = 0; i < 16; ++i) {
    double ga2 = (double)g * (double)W3[i * 4 + ch];
    gz2[i] = ga2 * (a2[i] > 0.0 ? 1.0 : a2[i] + 1.0);
  }
  double gd = 0.0, gatt = 0.0;
#pragma unroll
  for (int i = 0; i < 16; ++i) {
    double ga1 = 0.0;
#pragma unroll
    for (int jj = 0; jj < 16; ++jj) ga1 = fma(gz2[jj], (double)W2[i * 16 + jj], ga1);
    double gz1 = ga1 * (a1[i] > 0.0 ? 1.0 : a1[i] + 1.0);
    gd = fma(gz1, (double)W1[i], gd);
    gatt = fma(gz1, (double)W1[16 + i], gatt);
  }
  double inv = 1.0 / dist;
  atomicAdd(&dpoints[2 * pidx], (float)(gd * dx * inv));
  atomicAdd(&dpoints[2 * pidx + 1], (float)(gd * dy * inv));
  atomicAdd(&dattrs[pidx], (float)gatt);
}

__global__ __launch_bounds__(TPB)
void k_reduce(const float* __restrict__ dpoints, const float* __restrict__ dattrs,
              const float* __restrict__ gforce, const float* __restrict__ gattr,
              float* __restrict__ out) {
  int i = blockIdx.x * TPB + threadIdx.x;
  float dp0 = dpoints[2 * i], dp1 = dpoints[2 * i + 1], da = dattrs[i];
  float gf0 = gforce[2 * i], gf1 = gforce[2 * i + 1], ga = gattr[i];
  float e0 = dp0 - gf0, e1 = dp1 - gf1, e2 = da - ga;
  float c1v = e0 * e0 + e1 * e1;
  float c2v = e2 * e2;
  float sm = dp0 + dp1 + da;
  float ab = fabsf(dp0) + fabsf(dp1) + fabsf(da);
#pragma unroll
  for (int o = 32; o > 0; o >>= 1) {
    c1v += __shfl_down(c1v, o, 64);
    c2v += __shfl_down(c2v, o, 64);
    sm += __shfl_down(sm, o, 64);
    ab += __shfl_down(ab, o, 64);
  }
  __shared__ float red[4][4];
  int wv = threadIdx.x >> 6, ln = threadIdx.x & 63;
  if (ln == 0) { red[wv][0] = c1v; red[wv][1] = c2v; red[wv][2] = sm; red[wv][3] = ab; }
  __syncthreads();
  if (threadIdx.x == 0) {
    float C1 = 0, C2 = 0, S = 0, A = 0;
    for (int w = 0; w < 4; ++w) { C1 += red[w][0]; C2 += red[w][1]; S += red[w][2]; A += red[w][3]; }
    atomicAdd(&out[0], C1 * (1.0f / 4194304.0f) + C2 * (1.0f / 2097152.0f));
    atomicAdd(&out[1], S * (1.0f / 128.0f));
    atomicAdd(&out[2], A * (1.0f / 128.0f));
  }
}

extern "C" void kernel_launch(void* const* d_in, const int* in_sizes, int n_in,
                              void* d_out, int out_size, void* d_ws, size_t ws_size,
                              hipStream_t stream) {
  (void)in_sizes; (void)n_in; (void)ws_size;
  const float* points = (const float*)d_in[0];
  const float* attrs  = (const float*)d_in[1];
  const float* gforce = (const float*)d_in[2];
  const float* gattr  = (const float*)d_in[3];
  const float* W1 = (const float*)d_in[4];
  const float* b1 = (const float*)d_in[5];
  const float* W2 = (const float*)d_in[6];
  const float* b2 = (const float*)d_in[7];
  const float* W3 = (const float*)d_in[8];
  const float* b3 = (const float*)d_in[9];
  const float* c1w  = (const float*)d_in[10];
  const float* c1b  = (const float*)d_in[11];
  const float* bn1g = (const float*)d_in[12];
  const float* bn1b = (const float*)d_in[13];
  const float* cw = (const float*)d_in[14];
  const float* cb = (const float*)d_in[15];
  const float* bg = (const float*)d_in[16];
  const float* bb = (const float*)d_in[17];
  float* out = (float*)d_out;

  char* ws = (char*)d_ws;
  unsigned long long* gp = (unsigned long long*)(ws);
  unsigned int* widx = (unsigned int*)(ws + 921600);
  float* dgrid = (float*)(ws + 1382400);
  float* wT  = (float*)(ws + 1843200);
  float* wTb = (float*)(ws + 3481600);
  float* acts = (float*)(ws + 5120000);

  float* dpoints = out + 3;
  float* dattrs  = out + 3 + 4194304;

  hipMemsetAsync(d_out, 0, (size_t)out_size * sizeof(float), stream);
  k_init<<<450, TPB, 0, stream>>>(gp, widx);
  k_wtrans<<<1600, TPB, 0, stream>>>(cw, wT, wTb);
  k_point_fwd<<<8192, TPB, 0, stream>>>(points, attrs, W1, b1, W2, b2, W3, b3, gp);
  k_claim<<<8192, TPB, 0, stream>>>(points, attrs, W1, b1, W2, b2, W3, b3, gp, widx);
  k_cnn_fwd<<<128, 512, 0, stream>>>(gp, c1w, c1b, bn1g, bn1b, wT, cb, bg, bb, acts);
  k_cnn_bwd<<<128, 512, 0, stream>>>(acts, wTb, bg, c1w, bn1g, dgrid);
  k_winner<<<450, TPB, 0, stream>>>(points, attrs, W1, b1, W2, b2, W3, b3, widx, dgrid,
                                    dpoints, dattrs);
  k_reduce<<<8192, TPB, 0, stream>>>(dpoints, dattrs, gforce, gattr, out);
}

// Round 3
// 1715.293 us; speedup vs baseline: 2.8455x; 2.8455x over previous
//
#include <hip/hip_runtime.h>

#define TPB 256
#define PSTR 36   // LDS pixel stride (floats): 32ch + 4 pad -> bank spread + 16B align

// ---------------- workspace layout (bytes) ----------------
// gp   u64 [128*900]          @ 0          921600
// widx u32 [128*900]          @ 921600     460800
// dgrid f32 [128*900]         @ 1382400    460800
// wT   f32 [16*25*8*32*4]     @ 1843200    1638400   fwd weights [j][t][g][ci][c]
// wTb  f32 [16*25*8*32*4]     @ 3481600    1638400   bwd weights (tap-flipped, ch-swapped)
// acts f32 [128*17*32*64]     @ 5120000    17825792  activations [b][l][ch][pix]
// total ~22.9 MB

static __device__ __forceinline__ unsigned long long dkey(double d) {
  unsigned long long b = (unsigned long long)__double_as_longlong(d);
  return (b & 0x8000000000000000ull) ? ~b : (b | 0x8000000000000000ull);
}

// Deterministic fp64 point-MLP forward (explicit fma -> bit-identical across kernels)
static __device__ __forceinline__ void mlp_forward(
    float px, float py, float at,
    const float* __restrict__ W1, const float* __restrict__ b1,
    const float* __restrict__ W2, const float* __restrict__ b2,
    const float* __restrict__ W3, const float* __restrict__ b3,
    int& c0, int& c1, double& dx, double& dy, double& dist,
    double a1[16], double a2[16], double f[4]) {
  c0 = (int)floorf(px); c0 = c0 < 0 ? 0 : (c0 > 14 ? 14 : c0);
  c1 = (int)floorf(py); c1 = c1 < 0 ? 0 : (c1 > 14 ? 14 : c1);
  dx = (double)px - ((double)c0 + 0.5);
  dy = (double)py - ((double)c1 + 0.5);
  dist = sqrt(fma(dx, dx, fma(dy, dy, 1e-12)));
  double datt = (double)at;
#pragma unroll
  for (int j = 0; j < 16; ++j) {
    double z = fma(dist, (double)W1[j], fma(datt, (double)W1[16 + j], (double)b1[j]));
    a1[j] = z > 0.0 ? z : expm1(z);
  }
#pragma unroll
  for (int j = 0; j < 16; ++j) {
    double z = (double)b2[j];
#pragma unroll
    for (int i = 0; i < 16; ++i) z = fma(a1[i], (double)W2[i * 16 + j], z);
    a2[j] = z > 0.0 ? z : expm1(z);
  }
#pragma unroll
  for (int k = 0; k < 4; ++k) {
    double ff = (double)b3[k];
#pragma unroll
    for (int i = 0; i < 16; ++i) ff = fma(a2[i], (double)W3[i * 4 + k], ff);
    f[k] = ff;
  }
}

__global__ __launch_bounds__(TPB)
void k_init(unsigned long long* __restrict__ gp, unsigned int* __restrict__ widx) {
  int e = blockIdx.x * TPB + threadIdx.x;
  if (e < 128 * 900) { gp[e] = 0x8000000000000000ull; widx[e] = 0xFFFFFFFFu; }
}

// Transpose conv weights: wT[j][t][g][m=ci][c] = cw[j][co=g*4+c][ci=m][t]
//                         wTb[j][t][g][m=co][c] = cw[j][co=m][ci=g*4+c][24-t]
__global__ __launch_bounds__(TPB)
void k_wtrans(const float* __restrict__ cw, float* __restrict__ wT, float* __restrict__ wTb) {
  int i = blockIdx.x * TPB + threadIdx.x;
  if (i >= 409600) return;
  int c = i & 3;
  int m = (i >> 2) & 31;
  int g = (i >> 7) & 7;
  int jt = i >> 10;
  int t = jt % 25;
  int j = jt / 25;
  wT[i]  = cw[((size_t)(j * 32 + (g * 4 + c)) * 32 + m) * 25 + t];
  wTb[i] = cw[((size_t)(j * 32 + m) * 32 + (g * 4 + c)) * 25 + (24 - t)];
}

__global__ __launch_bounds__(TPB)
void k_point_fwd(const float* __restrict__ points, const float* __restrict__ attrs,
                 const float* __restrict__ W1, const float* __restrict__ b1,
                 const float* __restrict__ W2, const float* __restrict__ b2,
                 const float* __restrict__ W3, const float* __restrict__ b3,
                 unsigned long long* __restrict__ gp) {
  int gid = blockIdx.x * TPB + threadIdx.x;  // exactly 2^21 threads
  float px = points[2 * gid], py = points[2 * gid + 1];
  float at = attrs[gid];
  int c0, c1; double dx, dy, dist, a1[16], a2[16], f[4];
  mlp_forward(px, py, at, W1, b1, W2, b2, W3, b3, c0, c1, dx, dy, dist, a1, a2, f);
  int b = gid >> 14;
  size_t base = (size_t)b * 900 + (size_t)(c0 * 15 + c1) * 4;
#pragma unroll
  for (int k = 0; k < 4; ++k) atomicMax(&gp[base + k], dkey(f[k]));
}

__global__ __launch_bounds__(TPB)
void k_claim(const float* __restrict__ points, const float* __restrict__ attrs,
             const float* __restrict__ W1, const float* __restrict__ b1,
             const float* __restrict__ W2, const float* __restrict__ b2,
             const float* __restrict__ W3, const float* __restrict__ b3,
             const unsigned long long* __restrict__ gp, unsigned int* __restrict__ widx) {
  int gid = blockIdx.x * TPB + threadIdx.x;
  float px = points[2 * gid], py = points[2 * gid + 1];
  float at = attrs[gid];
  int c0, c1; double dx, dy, dist, a1[16], a2[16], f[4];
  mlp_forward(px, py, at, W1, b1, W2, b2, W3, b3, c0, c1, dx, dy, dist, a1, a2, f);
  int b = gid >> 14;
  size_t base = (size_t)b * 900 + (size_t)(c0 * 15 + c1) * 4;
#pragma unroll
  for (int k = 0; k < 4; ++k)
    if (dkey(f[k]) == gp[base + k]) atomicMin(&widx[base + k], (unsigned)(gid & 16383));
}

// 25-tap MAC block, spill-free: tap loops NOT unrolled (incremental offsets),
// only the 8x in-channel-block body unrolled. Weights are wave-uniform (s_load
// path); acts are ds_read_b128 from LDS [pix][ch] layout, stride PSTR.
static __device__ __forceinline__ void conv_mac(const float* __restrict__ Rd, int tap_base,
                                                const float* __restrict__ wb,
                                                float& acc0, float& acc1, float& acc2, float& acc3) {
  int po = tap_base;
  const float* wp = wb;
#pragma unroll 1
  for (int ky = 0; ky < 5; ++ky) {
#pragma unroll 1
    for (int kx = 0; kx < 5; ++kx) {
#pragma unroll
      for (int cib = 0; cib < 8; ++cib) {
        const float4 a4 = *(const float4*)&Rd[po + cib * 4];
        const float* w16 = wp + cib * 16;
        acc0 = fmaf(w16[0],  a4.x, acc0); acc1 = fmaf(w16[1],  a4.x, acc1);
        acc2 = fmaf(w16[2],  a4.x, acc2); acc3 = fmaf(w16[3],  a4.x, acc3);
        acc0 = fmaf(w16[4],  a4.y, acc0); acc1 = fmaf(w16[5],  a4.y, acc1);
        acc2 = fmaf(w16[6],  a4.y, acc2); acc3 = fmaf(w16[7],  a4.y, acc3);
        acc0 = fmaf(w16[8],  a4.z, acc0); acc1 = fmaf(w16[9],  a4.z, acc1);
        acc2 = fmaf(w16[10], a4.z, acc2); acc3 = fmaf(w16[11], a4.z, acc3);
        acc0 = fmaf(w16[12], a4.w, acc0); acc1 = fmaf(w16[13], a4.w, acc1);
        acc2 = fmaf(w16[14], a4.w, acc2); acc3 = fmaf(w16[15], a4.w, acc3);
      }
      po += PSTR;       // next kx: pixel + 1
      wp += 1024;       // next tap: [t] stride = 8 groups * 128
    }
    po += 7 * PSTR;     // next ky: +12 pixels total (5 already added)
  }
}

__global__ __launch_bounds__(512, 2)
void k_cnn_fwd(const unsigned long long* __restrict__ gp,
               const float* __restrict__ c1w, const float* __restrict__ c1b,
               const float* __restrict__ bn1g, const float* __restrict__ bn1b,
               const float* __restrict__ wT, const float* __restrict__ cb,
               const float* __restrict__ bg, const float* __restrict__ bb,
               float* __restrict__ acts) {
  __shared__ float xin[900];
  __shared__ __align__(16) float buf[2][5184];  // [12x12 pix][36] x2 ping-pong
  const int tid = threadIdx.x;
  const int b = blockIdx.x;
  for (int t = tid; t < 10368; t += 512) ((float*)buf)[t] = 0.0f;
  for (int t = tid; t < 900; t += 512) {
    int c = t / 225, rem = t - c * 225;
    unsigned long long k = gp[(size_t)b * 900 + rem * 4 + c];
    long long bits = (k & 0x8000000000000000ull) ? (long long)(k & 0x7FFFFFFFFFFFFFFFull)
                                                 : ~(long long)k;
    xin[c * 225 + rem] = (float)__longlong_as_double(bits);
  }
  __syncthreads();
  const float rs = sqrtf(1.0f + 1e-5f);
  // conv1: 4x15x15 -> 32x8x8, stride 2, pad 2
  for (int k = tid; k < 2048; k += 512) {
    int co = k >> 6, pix = k & 63, y = pix >> 3, x = pix & 7;
    float acc = c1b[co];
    for (int ci = 0; ci < 4; ++ci)
#pragma unroll
      for (int ky = 0; ky < 5; ++ky) {
        int iy = 2 * y + ky - 2;
        if (iy < 0 || iy > 14) continue;
#pragma unroll
        for (int kx = 0; kx < 5; ++kx) {
          int ix = 2 * x + kx - 2;
          if (ix < 0 || ix > 14) continue;
          acc = fmaf(c1w[((co * 4 + ci) * 5 + ky) * 5 + kx], xin[ci * 225 + iy * 15 + ix], acc);
        }
      }
    float z = fmaf(acc, bn1g[co] / rs, bn1b[co]);
    float a = z > 0.f ? z : expm1f(z);
    buf[0][((y + 2) * 12 + (x + 2)) * PSTR + co] = a;
    acts[((size_t)(b * 17) * 32 + co) * 64 + pix] = a;
  }
  __syncthreads();
  const int wave = __builtin_amdgcn_readfirstlane(tid >> 6);  // 0..7, 4 out-ch each
  const int lane = tid & 63;
  const int y = lane >> 3, x = lane & 7;
  const int tap_base = (y * 12 + x) * PSTR;
  const int st_off = ((y + 2) * 12 + (x + 2)) * PSTR + wave * 4;
  float* B0 = buf[0];
  float* B1 = buf[1];
#pragma unroll 1
  for (int j = 0; j < 16; ++j) {
    const float* Rd = (j & 1) ? B1 : B0;
    float* Wr = (j & 1) ? B0 : B1;
    const float* wb = wT + ((size_t)(j * 25) * 8 + wave) * 128;
    const int cbase = j * 32 + wave * 4;
    float acc0 = cb[cbase], acc1 = cb[cbase + 1], acc2 = cb[cbase + 2], acc3 = cb[cbase + 3];
    conv_mac(Rd, tap_base, wb, acc0, acc1, acc2, acc3);
    float z0 = fmaf(acc0, bg[cbase] / rs, bb[cbase]);
    float z1 = fmaf(acc1, bg[cbase + 1] / rs, bb[cbase + 1]);
    float z2 = fmaf(acc2, bg[cbase + 2] / rs, bb[cbase + 2]);
    float z3 = fmaf(acc3, bg[cbase + 3] / rs, bb[cbase + 3]);
    float a0 = z0 > 0.f ? z0 : expm1f(z0);
    float a1 = z1 > 0.f ? z1 : expm1f(z1);
    float a2 = z2 > 0.f ? z2 : expm1f(z2);
    float a3 = z3 > 0.f ? z3 : expm1f(z3);
    *(float4*)&Wr[st_off] = make_float4(a0, a1, a2, a3);
    float* ap = acts + ((size_t)(b * 17 + j + 1) * 32 + wave * 4) * 64 + lane;
    ap[0] = a0; ap[64] = a1; ap[128] = a2; ap[192] = a3;
    __syncthreads();
  }
}

__global__ __launch_bounds__(512, 2)
void k_cnn_bwd(const float* __restrict__ acts,
               const float* __restrict__ wTb, const float* __restrict__ bg,
               const float* __restrict__ c1w, const float* __restrict__ bn1g,
               float* __restrict__ dgrid) {
  __shared__ __align__(16) float buf[2][5184];
  const int tid = threadIdx.x;
  const int b = blockIdx.x;
  for (int t = tid; t < 10368; t += 512) ((float*)buf)[t] = 0.0f;
  __syncthreads();
  for (int k = tid; k < 2048; k += 512) {
    int pix = k >> 5, ch = k & 31;
    buf[0][((2 + (pix >> 3)) * 12 + 2 + (pix & 7)) * PSTR + ch] = 1.0f / 2048.0f;
  }
  __syncthreads();
  const float rs = sqrtf(1.0f + 1e-5f);
  const int wave = __builtin_amdgcn_readfirstlane(tid >> 6);
  const int lane = tid & 63;
  const int y = lane >> 3, x = lane & 7;
  const int tap_base = (y * 12 + x) * PSTR;
  const int st_off = ((y + 2) * 12 + (x + 2)) * PSTR + wave * 4;
  const int sch = tid >> 4;           // scale step: channel
  const int sp4 = (tid & 15) * 4;     // scale step: pixel quad
  float* B0 = buf[0];
  float* B1 = buf[1];
#pragma unroll 1
  for (int jj = 0; jj < 16; ++jj) {
    const int j = 15 - jj;
    float* G  = (jj & 1) ? B1 : B0;
    float* Wr = (jj & 1) ? B0 : B1;
    // scale: G *= elu'(act_{j+1}) * bg/rs
    {
      const float4 a = *(const float4*)&acts[((size_t)(b * 17 + j + 1) * 32 + sch) * 64 + sp4];
      const float sj = bg[j * 32 + sch] / rs;
#pragma unroll
      for (int q = 0; q < 4; ++q) {
        int pix = sp4 + q;
        int li = ((2 + (pix >> 3)) * 12 + 2 + (pix & 7)) * PSTR + sch;
        float av = q == 0 ? a.x : (q == 1 ? a.y : (q == 2 ? a.z : a.w));
        float d = (av > 0.f ? 1.f : av + 1.f) * sj;
        G[li] *= d;
      }
    }
    __syncthreads();
    // transposed conv (tap-flipped weights, channels swapped)
    const float* wb = wTb + ((size_t)(j * 25) * 8 + wave) * 128;
    float acc0 = 0.f, acc1 = 0.f, acc2 = 0.f, acc3 = 0.f;
    conv_mac(G, tap_base, wb, acc0, acc1, acc2, acc3);
    *(float4*)&Wr[st_off] = make_float4(acc0, acc1, acc2, acc3);
    __syncthreads();
  }
  // final grad lives in B0; scale by elu'(act_0) * bn1g/rs
  {
    const float4 a = *(const float4*)&acts[((size_t)(b * 17) * 32 + sch) * 64 + sp4];
    const float sj = bn1g[sch] / rs;
#pragma unroll
    for (int q = 0; q < 4; ++q) {
      int pix = sp4 + q;
      int li = ((2 + (pix >> 3)) * 12 + 2 + (pix & 7)) * PSTR + sch;
      float av = q == 0 ? a.x : (q == 1 ? a.y : (q == 2 ? a.z : a.w));
      float d = (av > 0.f ? 1.f : av + 1.f) * sj;
      B0[li] *= d;
    }
  }
  __syncthreads();
  // conv1 backward to the 4x15x15 grid input
  for (int e = tid; e < 900; e += 512) {
    int cid = e >> 2, ci = e & 3;
    int u = cid / 15, v = cid - u * 15;
    float acc = 0.f;
    for (int co = 0; co < 32; ++co) {
      const float* wp = c1w + (co * 4 + ci) * 25;
#pragma unroll
      for (int ky = 0; ky < 5; ++ky) {
        int t2 = u + 2 - ky;
        if (t2 < 0 || t2 > 14 || (t2 & 1)) continue;
        int yy = t2 >> 1;
#pragma unroll
        for (int kx = 0; kx < 5; ++kx) {
          int s2 = v + 2 - kx;
          if (s2 < 0 || s2 > 14 || (s2 & 1)) continue;
          int xq = s2 >> 1;
          acc = fmaf(wp[ky * 5 + kx], B0[((yy + 2) * 12 + (xq + 2)) * PSTR + co], acc);
        }
      }
    }
    dgrid[(size_t)b * 900 + e] = acc;
  }
}

__global__ __launch_bounds__(TPB)
void k_winner(const float* __restrict__ points, const float* __restrict__ attrs,
              const float* __restrict__ W1, const float* __restrict__ b1,
              const float* __restrict__ W2, const float* __restrict__ b2,
              const float* __restrict__ W3, const float* __restrict__ b3,
              const unsigned int* __restrict__ widx, const float* __restrict__ dgrid,
              float* __restrict__ dpoints, float* __restrict__ dattrs) {
  int e = blockIdx.x * TPB + threadIdx.x;  // exactly 115200
  unsigned pi = widx[e];
  if (pi == 0xFFFFFFFFu) return;
  float g = dgrid[e];
  if (g == 0.f) return;
  int b = e / 900;
  int r = e - b * 900;
  int ch = r & 3;
  size_t pidx = ((size_t)b << 14) + pi;
  float px = points[2 * pidx], py = points[2 * pidx + 1], at = attrs[pidx];
  int c0, c1; double dx, dy, dist, a1[16], a2[16], f[4];
  mlp_forward(px, py, at, W1, b1, W2, b2, W3, b3, c0, c1, dx, dy, dist, a1, a2, f);
  double gz2[16];
#pragma unroll
  for (int i = 0; i < 16; ++i) {
    double ga2 = (double)g * (double)W3[i * 4 + ch];
    gz2[i] = ga2 * (a2[i] > 0.0 ? 1.0 : a2[i] + 1.0);
  }
  double gd = 0.0, gatt = 0.0;
#pragma unroll
  for (int i = 0; i < 16; ++i) {
    double ga1 = 0.0;
#pragma unroll
    for (int jj = 0; jj < 16; ++jj) ga1 = fma(gz2[jj], (double)W2[i * 16 + jj], ga1);
    double gz1 = ga1 * (a1[i] > 0.0 ? 1.0 : a1[i] + 1.0);
    gd = fma(gz1, (double)W1[i], gd);
    gatt = fma(gz1, (double)W1[16 + i], gatt);
  }
  double inv = 1.0 / dist;
  atomicAdd(&dpoints[2 * pidx], (float)(gd * dx * inv));
  atomicAdd(&dpoints[2 * pidx + 1], (float)(gd * dy * inv));
  atomicAdd(&dattrs[pidx], (float)gatt);
}

__global__ __launch_bounds__(TPB)
void k_reduce(const float* __restrict__ dpoints, const float* __restrict__ dattrs,
              const float* __restrict__ gforce, const float* __restrict__ gattr,
              float* __restrict__ out) {
  int i = blockIdx.x * TPB + threadIdx.x;
  float dp0 = dpoints[2 * i], dp1 = dpoints[2 * i + 1], da = dattrs[i];
  float gf0 = gforce[2 * i], gf1 = gforce[2 * i + 1], ga = gattr[i];
  float e0 = dp0 - gf0, e1 = dp1 - gf1, e2 = da - ga;
  float c1v = e0 * e0 + e1 * e1;
  float c2v = e2 * e2;
  float sm = dp0 + dp1 + da;
  float ab = fabsf(dp0) + fabsf(dp1) + fabsf(da);
#pragma unroll
  for (int o = 32; o > 0; o >>= 1) {
    c1v += __shfl_down(c1v, o, 64);
    c2v += __shfl_down(c2v, o, 64);
    sm += __shfl_down(sm, o, 64);
    ab += __shfl_down(ab, o, 64);
  }
  __shared__ float red[4][4];
  int wv = threadIdx.x >> 6, ln = threadIdx.x & 63;
  if (ln == 0) { red[wv][0] = c1v; red[wv][1] = c2v; red[wv][2] = sm; red[wv][3] = ab; }
  __syncthreads();
  if (threadIdx.x == 0) {
    float C1 = 0, C2 = 0, S = 0, A = 0;
    for (int w = 0; w < 4; ++w) { C1 += red[w][0]; C2 += red[w][1]; S += red[w][2]; A += red[w][3]; }
    atomicAdd(&out[0], C1 * (1.0f / 4194304.0f) + C2 * (1.0f / 2097152.0f));
    atomicAdd(&out[1], S * (1.0f / 128.0f));
    atomicAdd(&out[2], A * (1.0f / 128.0f));
  }
}

extern "C" void kernel_launch(void* const* d_in, const int* in_sizes, int n_in,
                              void* d_out, int out_size, void* d_ws, size_t ws_size,
                              hipStream_t stream) {
  (void)in_sizes; (void)n_in; (void)ws_size;
  const float* points = (const float*)d_in[0];
  const float* attrs  = (const float*)d_in[1];
  const float* gforce = (const float*)d_in[2];
  const float* gattr  = (const float*)d_in[3];
  const float* W1 = (const float*)d_in[4];
  const float* b1 = (const float*)d_in[5];
  const float* W2 = (const float*)d_in[6];
  const float* b2 = (const float*)d_in[7];
  const float* W3 = (const float*)d_in[8];
  const float* b3 = (const float*)d_in[9];
  const float* c1w  = (const float*)d_in[10];
  const float* c1b  = (const float*)d_in[11];
  const float* bn1g = (const float*)d_in[12];
  const float* bn1b = (const float*)d_in[13];
  const float* cw = (const float*)d_in[14];
  const float* cb = (const float*)d_in[15];
  const float* bg = (const float*)d_in[16];
  const float* bb = (const float*)d_in[17];
  float* out = (float*)d_out;

  char* ws = (char*)d_ws;
  unsigned long long* gp = (unsigned long long*)(ws);
  unsigned int* widx = (unsigned int*)(ws + 921600);
  float* dgrid = (float*)(ws + 1382400);
  float* wT  = (float*)(ws + 1843200);
  float* wTb = (float*)(ws + 3481600);
  float* acts = (float*)(ws + 5120000);

  float* dpoints = out + 3;
  float* dattrs  = out + 3 + 4194304;

  hipMemsetAsync(d_out, 0, (size_t)out_size * sizeof(float), stream);
  k_init<<<450, TPB, 0, stream>>>(gp, widx);
  k_wtrans<<<1600, TPB, 0, stream>>>(cw, wT, wTb);
  k_point_fwd<<<8192, TPB, 0, stream>>>(points, attrs, W1, b1, W2, b2, W3, b3, gp);
  k_claim<<<8192, TPB, 0, stream>>>(points, attrs, W1, b1, W2, b2, W3, b3, gp, widx);
  k_cnn_fwd<<<128, 512, 0, stream>>>(gp, c1w, c1b, bn1g, bn1b, wT, cb, bg, bb, acts);
  k_cnn_bwd<<<128, 512, 0, stream>>>(acts, wTb, bg, c1w, bn1g, dgrid);
  k_winner<<<450, TPB, 0, stream>>>(points, attrs, W1, b1, W2, b2, W3, b3, widx, dgrid,
                                    dpoints, dattrs);
  k_reduce<<<8192, TPB, 0, stream>>>(dpoints, dattrs, gforce, gattr, out);
}